// Round 12
// baseline (36.198 us; speedup 1.0000x reference)
//
#include <hip/hip_runtime.h>
#include <hip/hip_fp16.h>
#include <math.h>

constexpr int D    = 1024;
constexpr int NEXP = 4;
constexpr int EPP  = 2048;

typedef _Float16 f16x8 __attribute__((ext_vector_type(8)));
typedef float    f32x4 __attribute__((ext_vector_type(4)));

__device__ __forceinline__ unsigned pk2(float a, float b) {
    return __builtin_bit_cast(unsigned, __builtin_amdgcn_cvt_pkrtz(a, b));
}
__device__ __forceinline__ f16x8 cvt8(const float* p) {
    const float4 u = *reinterpret_cast<const float4*>(p);
    const float4 v = *reinterpret_cast<const float4*>(p + 4);
    const uint4 w = make_uint4(pk2(u.x, u.y), pk2(u.z, u.w), pk2(v.x, v.y), pk2(v.z, v.w));
    return __builtin_bit_cast(f16x8, w);
}

// ---------------- K1: prep (blocks 0..63) + router (blocks 64..) ----------------
__global__ __launch_bounds__(256) void prep_router_kernel(
    const float* __restrict__ h, const float* __restrict__ lts,
    const float* __restrict__ Wr, const float* __restrict__ br,
    float* __restrict__ out_ew, int* __restrict__ eidx,
    _Float16* __restrict__ lts16, _Float16* __restrict__ ltsT, int ntok)
{
    const int tid = threadIdx.x;

    if (blockIdx.x < 64) {
        // ---- prep: f16 slice copies ----
        const int e = blockIdx.x >> 4, part = (blockIdx.x >> 2) & 3, dc = blockIdx.x & 3;
        __shared__ __align__(16) _Float16 s[8][256];

        const float4* src = reinterpret_cast<const float4*>(lts);
        #pragma unroll
        for (int i = 0; i < 2; ++i) {
            const int f = tid + 256 * i;
            const int r = f >> 6, c4 = f & 63;
            const float4 v = src[(size_t)(e * EPP + part * 8 + r) * 256 + dc * 64 + c4];
            *reinterpret_cast<uint2*>(&s[r][c4 * 4]) = make_uint2(pk2(v.x, v.y), pk2(v.z, v.w));
        }
        __syncthreads();

        {   // row-major copy
            const int r = tid >> 5, c = tid & 31;
            *reinterpret_cast<uint4*>(lts16 + (size_t)(e * 32 + part * 8 + r) * D + dc * 256 + c * 8) =
                *reinterpret_cast<const uint4*>(&s[r][c * 8]);
        }
        {   // transposed copy
            _Float16 tmp[8];
            #pragma unroll
            for (int k = 0; k < 8; ++k) tmp[k] = s[k][tid];
            *reinterpret_cast<uint4*>(ltsT + ((size_t)e << 15) + (size_t)(dc * 256 + tid) * 32 + part * 8) =
                *reinterpret_cast<const uint4*>(tmp);
        }
        return;
    }

    // ---- router: 1 token per wave; outputs only ew + eidx ----
    const int wid = tid >> 6, lane = tid & 63;
    const int tok = (blockIdx.x - 64) * 4 + wid;
    if (tok >= ntok) return;

    const float4* h4 = reinterpret_cast<const float4*>(h);
    const float4* w4 = reinterpret_cast<const float4*>(Wr);

    float acc[NEXP] = {0.f, 0.f, 0.f, 0.f};
    #pragma unroll
    for (int i = 0; i < 4; ++i) {
        const float4 a = h4[(size_t)tok * 256 + lane + 64 * i];
        #pragma unroll
        for (int e = 0; e < NEXP; ++e) {
            const float4 w = w4[e * 256 + lane + 64 * i];
            acc[e] += a.x * w.x + a.y * w.y + a.z * w.z + a.w * w.w;
        }
    }
    #pragma unroll
    for (int m = 1; m < 64; m <<= 1)
        #pragma unroll
        for (int e = 0; e < NEXP; ++e) acc[e] += __shfl_xor(acc[e], m);

    const float l0 = acc[0] + br[0], l1 = acc[1] + br[1],
                l2 = acc[2] + br[2], l3 = acc[3] + br[3];
    const float lm = fmaxf(fmaxf(l0, l1), fmaxf(l2, l3));
    const float e0 = __expf(l0 - lm), e1 = __expf(l1 - lm),
                e2 = __expf(l2 - lm), e3 = __expf(l3 - lm);
    const float einv = 1.f / (e0 + e1 + e2 + e3);
    if (lane < NEXP) {
        const float ev = (lane == 0) ? e0 : (lane == 1) ? e1 : (lane == 2) ? e2 : e3;
        out_ew[(size_t)tok * NEXP + lane] = ev * einv;
    }
    int bi = 0; float bv = l0;
    if (l1 > bv) { bv = l1; bi = 1; }
    if (l2 > bv) { bv = l2; bi = 2; }
    if (l3 > bv) { bv = l3; bi = 3; }
    if (lane == 0) eidx[tok] = bi;
}

// ---------------- K2: qk + softmax + pv, one (expert, 16-token chunk) ----------------
// A-frags built inline from f32 h (L3-resident); otherwise identical verified
// structure: K-split QK across waves, LDS partial reduce, 16-thr softmax,
// PV = P(16x32).V_e(32x1024) with 16 N-tiles per wave.
__global__ __launch_bounds__(256) void qkpv_kernel(
    const float* __restrict__ h, const _Float16* __restrict__ lts16,
    const _Float16* __restrict__ ltsT, const int* __restrict__ eidx,
    float* __restrict__ out_res, int ntok, int chunks)
{
    const int e = blockIdx.x / chunks;
    const int chunk = blockIdx.x - e * chunks;
    const int base = chunk * 16;

    const int tid = threadIdx.x, wid = tid >> 6, lane = tid & 63;
    __shared__ int eix[16];
    __shared__ float S_part[4][16][33];                  // 8.25 KB
    __shared__ __align__(16) _Float16 P[16][32];         // 1 KB

    if (tid < 16) {
        const int tk = base + tid;
        eix[tid] = (tk < ntok) ? eidx[tk] : -1;
    }

    const int rA = lane & 15, g4 = lane >> 4;
    int hr = base + rA; if (hr > ntok - 1) hr = ntok - 1;
    const float*     ap  = h     + (size_t)hr * D + g4 * 8;
    const _Float16* b0p = lts16 + (size_t)(e * 32 + rA) * D + g4 * 8;
    const _Float16* b1p = b0p + 16 * D;

    // ---- QK: wave wid covers kc in [wid*8, wid*8+8) ----
    f32x4 s0 = {0.f, 0.f, 0.f, 0.f}, s1 = {0.f, 0.f, 0.f, 0.f};
    #pragma unroll
    for (int k = 0; k < 8; ++k) {
        const int kc = wid * 8 + k;
        const f16x8 a  = cvt8(ap + kc * 32);
        const f16x8 b0 = *reinterpret_cast<const f16x8*>(b0p + kc * 32);
        const f16x8 b1 = *reinterpret_cast<const f16x8*>(b1p + kc * 32);
        s0 = __builtin_amdgcn_mfma_f32_16x16x32_f16(a, b0, s0, 0, 0, 0);
        s1 = __builtin_amdgcn_mfma_f32_16x16x32_f16(a, b1, s1, 0, 0, 0);
    }
    #pragma unroll
    for (int r = 0; r < 4; ++r) {
        S_part[wid][g4 * 4 + r][rA]      = s0[r];
        S_part[wid][g4 * 4 + r][rA + 16] = s1[r];
    }
    __syncthreads();

    // ---- reduce + softmax: thread -> (token tr, cols sl & sl+16) ----
    {
        const int tr = tid >> 4, sl = tid & 15;
        const float v0 = S_part[0][tr][sl] + S_part[1][tr][sl]
                       + S_part[2][tr][sl] + S_part[3][tr][sl];
        const float v1 = S_part[0][tr][sl + 16] + S_part[1][tr][sl + 16]
                       + S_part[2][tr][sl + 16] + S_part[3][tr][sl + 16];
        constexpr float inv32 = 1.f / 32.f;              // 1/sqrt(1024)
        float mx = fmaxf(v0, v1);
        #pragma unroll
        for (int m = 1; m < 16; m <<= 1) mx = fmaxf(mx, __shfl_xor(mx, m));
        const float p0 = __expf((v0 - mx) * inv32);
        const float p1 = __expf((v1 - mx) * inv32);
        float sm = p0 + p1;
        #pragma unroll
        for (int m = 1; m < 16; m <<= 1) sm += __shfl_xor(sm, m);
        const float is = 1.f / sm;
        P[tr][sl]      = (_Float16)(p0 * is);
        P[tr][sl + 16] = (_Float16)(p1 * is);
    }
    __syncthreads();

    // ---- PV: wave wid owns dims [wid*256, wid*256+256) ----
    const f16x8 pa = *reinterpret_cast<const f16x8*>(&P[rA][g4 * 8]);
    const _Float16* vtE = ltsT + ((size_t)e << 15);

    #pragma unroll
    for (int i = 0; i < 16; ++i) {
        const int dimc = wid * 256 + i * 16 + rA;
        const f16x8 bk = *reinterpret_cast<const f16x8*>(vtE + (size_t)dimc * 32 + g4 * 8);
        f32x4 o = {0.f, 0.f, 0.f, 0.f};
        o = __builtin_amdgcn_mfma_f32_16x16x32_f16(pa, bk, o, 0, 0, 0);
        #pragma unroll
        for (int r = 0; r < 4; ++r) {
            const int tr2 = g4 * 4 + r;
            if (base + tr2 < ntok && eix[tr2] == e)
                out_res[(size_t)(base + tr2) * D + dimc] = o[r];
        }
    }
}

extern "C" void kernel_launch(void* const* d_in, const int* in_sizes, int n_in,
                              void* d_out, int out_size, void* d_ws, size_t ws_size,
                              hipStream_t stream) {
    const float* h   = (const float*)d_in[0];
    const float* lts = (const float*)d_in[1];
    const float* Wr  = (const float*)d_in[2];
    const float* br  = (const float*)d_in[3];

    const int ntok = in_sizes[0] / D;            // b*t = 4096
    float* out_res = (float*)d_out;              // (b,t,d)
    float* out_ew  = out_res + (size_t)ntok * D; // (b,t,NEXP)

    _Float16* lts16 = (_Float16*)d_ws;                    // 128x1024 (256 KB)
    _Float16* ltsT  = lts16 + (size_t)128 * D;            // 4x1024x32 (256 KB)
    int*      eidx  = (int*)(ltsT + (size_t)NEXP * D * 32);

    const int chunks = (ntok + 15) / 16;         // 256

    const int rblocks = 64 + (ntok + 3) / 4;     // 64 prep + 1024 router
    prep_router_kernel<<<rblocks, 256, 0, stream>>>(h, lts, Wr, br, out_ew, eidx,
                                                    lts16, ltsT, ntok);
    qkpv_kernel<<<NEXP * chunks, 256, 0, stream>>>(h, lts16, ltsT, eidx,
                                                   out_res, ntok, chunks);
}